// Round 1
// baseline (455.711 us; speedup 1.0000x reference)
//
#include <hip/hip_runtime.h>

#define D_IMG 1024
#define K_DIM 3
#define O_IMG 1022   // D - K + 1
#define RPT   8      // output rows per thread

__global__ __launch_bounds__(256) void conv3x3_kernel(
    const float* __restrict__ in,   // [B, D, D]
    const float* __restrict__ w,    // [3,3]
    float* __restrict__ out)        // [B, O, O]
{
    const int strips_per_img = (O_IMG + RPT - 1) / RPT;   // 128
    const int bid   = blockIdx.x;
    const int img   = bid / strips_per_img;
    const int strip = bid % strips_per_img;
    const int y0    = strip * RPT;
    const int x0    = threadIdx.x * 4;

    const float* ip = in  + (size_t)img * (D_IMG * D_IMG);
    float*       op = out + (size_t)img * ((size_t)O_IMG * O_IMG);

    // kernel weights: uniform indices -> scalar loads
    const float k00 = w[0], k01 = w[1], k02 = w[2];
    const float k10 = w[3], k11 = w[4], k12 = w[5];
    const float k20 = w[6], k21 = w[7], k22 = w[8];

    const bool tail = (x0 + 8 > D_IMG);   // only x0 == 1020 (lane 255)

    float r[3][8];

    auto loadrow = [&](int y, float* dst) {
        const float4 a = *(const float4*)(ip + (size_t)y * D_IMG + x0);
        dst[0] = a.x; dst[1] = a.y; dst[2] = a.z; dst[3] = a.w;
        if (!tail) {
            const float4 b = *(const float4*)(ip + (size_t)y * D_IMG + x0 + 4);
            dst[4] = b.x; dst[5] = b.y; dst[6] = b.z; dst[7] = b.w;
        } else {
            dst[4] = dst[5] = dst[6] = dst[7] = 0.f;
        }
    };

    loadrow(y0,     r[0]);
    loadrow(y0 + 1, r[1]);

    #pragma unroll
    for (int i = 0; i < RPT; ++i) {
        const int y = y0 + i;
        if (y >= O_IMG) break;           // last strip has 6 valid rows
        loadrow(y + 2, r[(i + 2) % 3]);  // max row read = 1023, in range

        const float* a = r[(i + 0) % 3];
        const float* b = r[(i + 1) % 3];
        const float* c = r[(i + 2) % 3];

        float acc[4];
        #pragma unroll
        for (int j = 0; j < 4; ++j) {
            acc[j] = a[j] * k00 + a[j+1] * k01 + a[j+2] * k02
                   + b[j] * k10 + b[j+1] * k11 + b[j+2] * k12
                   + c[j] * k20 + c[j+1] * k21 + c[j+2] * k22;
        }

        float* orow = op + (size_t)y * O_IMG + x0;
        if (!tail) {
            // output row stride 4088 B: 16B-misaligned on odd rows -> float2 x2
            *(float2*)(orow + 0) = make_float2(acc[0], acc[1]);
            *(float2*)(orow + 2) = make_float2(acc[2], acc[3]);
        } else {
            orow[0] = acc[0];
            orow[1] = acc[1];
        }
    }
}

extern "C" void kernel_launch(void* const* d_in, const int* in_sizes, int n_in,
                              void* d_out, int out_size, void* d_ws, size_t ws_size,
                              hipStream_t stream) {
    const float* in = (const float*)d_in[0];   // [64, 1024*1024] fp32
    const float* w  = (const float*)d_in[1];   // [3,3] fp32
    float* out      = (float*)d_out;           // [64, 1022*1022] fp32

    const int B = 64;
    const int strips_per_img = (O_IMG + RPT - 1) / RPT;  // 128
    dim3 grid(B * strips_per_img);                        // 8192 blocks
    dim3 block(256);
    conv3x3_kernel<<<grid, block, 0, stream>>>(in, w, out);
}